// Round 9
// baseline (721.857 us; speedup 1.0000x reference)
//
#include <hip/hip_runtime.h>
#include <hip/hip_cooperative_groups.h>
#include <math.h>

namespace cg = cooperative_groups;

constexpr int Bn = 1024, DH = 2048, K1 = 4096, DO = 1024, NL = 128;
constexpr int MN = Bn * DO;  // 1M elements

typedef __bf16 bf16x8 __attribute__((ext_vector_type(8)));
typedef short  s16x8  __attribute__((ext_vector_type(8)));
typedef float  f32x4  __attribute__((ext_vector_type(4)));

__device__ __forceinline__ unsigned short f2bf(float f) {
  union { float f; unsigned u; } v; v.f = f;
  unsigned r = v.u + 0x7FFFu + ((v.u >> 16) & 1u);  // RNE
  return (unsigned short)(r >> 16);
}
__device__ __forceinline__ float bf2f(unsigned short h) {
  union { unsigned u; float f; } v; v.u = ((unsigned)h) << 16; return v.f;
}

// ============================================================================
// MEGA (cooperative) PATH — all phases in one kernel, LDS <= 16384 B so the
// cooperative capacity check (64 KB/CU accounting) still gives 4 blocks/CU.
// ============================================================================
constexpr int SMEM_BYTES = 16384;

// gemm phase: 64x64 tile, 4 waves each owning a 32x32 quadrant (no in-block
// k-split => no LDS reduce), BK=64 (LA+LB = 16 KB), block split-K over z,
// XCD-aware swizzle. Writes fp32 partials P[z][1024][1024].
__device__ __forceinline__ void gemm_phase(
    const unsigned short* __restrict__ A, const unsigned short* __restrict__ Bt,
    float* __restrict__ P, int K, int KSLICE, char* smem, int bid, int tid) {
  unsigned short* LA = (unsigned short*)smem;         // 64 rows x 8 chunks x 8 bf16 = 8 KB
  unsigned short* LB = (unsigned short*)smem + 4096;  // 8 KB

  const int w = tid >> 6, l = tid & 63;
  // bid = g + 8*(ix + 4*iy + 32*z), g = gx + 4*gy -> XCD g owns a 4x2 supertile
  const int g = bid & 7, t = bid >> 3;
  const int x = (g & 3) * 4 + (t & 3);
  const int y = (g >> 2) * 8 + ((t >> 2) & 7);
  const int z = t >> 5;
  const int m0 = y * 64, n0 = x * 64;
  const int kb = z * KSLICE;

  f32x4 acc[2][2] = {};

  const int NIT = KSLICE / 64;
  for (int it = 0; it < NIT; ++it) {
    const int k0 = kb + it * 64;
    #pragma unroll
    for (int i = 0; i < 2; ++i) {  // A: 512 slots (row, chunk-of-8), 2/thread
      const int c = i * 256 + tid, row = c >> 3, kc = c & 7;
      const int kcg = kc ^ (row & 7);
      __builtin_amdgcn_global_load_lds(
          (const __attribute__((address_space(1))) unsigned int*)(A + (size_t)(m0 + row) * K + k0 + kcg * 8),
          (__attribute__((address_space(3))) unsigned int*)&LA[c * 8], 16, 0, 0);
    }
    #pragma unroll
    for (int i = 0; i < 2; ++i) {  // B
      const int c = i * 256 + tid, row = c >> 3, kc = c & 7;
      const int kcg = kc ^ (row & 7);
      __builtin_amdgcn_global_load_lds(
          (const __attribute__((address_space(1))) unsigned int*)(Bt + (size_t)(n0 + row) * K + k0 + kcg * 8),
          (__attribute__((address_space(3))) unsigned int*)&LB[c * 8], 16, 0, 0);
    }
    __syncthreads();

    #pragma unroll
    for (int s = 0; s < 2; ++s) {  // two 32-k MFMA steps cover BK=64
      bf16x8 af[2], bfr[2];
      #pragma unroll
      for (int i = 0; i < 2; ++i) {
        const int r = (w >> 1) * 32 + i * 16 + (l & 15);
        const int kca = (s * 4 + (l >> 4)) ^ (r & 7);
        af[i] = __builtin_bit_cast(bf16x8, *(const s16x8*)&LA[(r * 8 + kca) * 8]);
      }
      #pragma unroll
      for (int j = 0; j < 2; ++j) {
        const int rr = (w & 1) * 32 + j * 16 + (l & 15);
        const int kcb = (s * 4 + (l >> 4)) ^ (rr & 7);
        bfr[j] = __builtin_bit_cast(bf16x8, *(const s16x8*)&LB[(rr * 8 + kcb) * 8]);
      }
      #pragma unroll
      for (int i = 0; i < 2; ++i)
        #pragma unroll
        for (int j = 0; j < 2; ++j)
          acc[i][j] = __builtin_amdgcn_mfma_f32_16x16x32_bf16(af[i], bfr[j], acc[i][j], 0, 0, 0);
    }
    __syncthreads();
  }

  // store quadrant partials (C/D: col=l&15 -> n, row=(l>>4)*4+r -> m)
  float* Pz = P + (size_t)z * MN;
  #pragma unroll
  for (int i = 0; i < 2; ++i) {
    #pragma unroll
    for (int r = 0; r < 4; ++r) {
      const int m = m0 + (w >> 1) * 32 + i * 16 + (l >> 4) * 4 + r;
      #pragma unroll
      for (int j = 0; j < 2; ++j) {
        const int n = n0 + (w & 1) * 32 + j * 16 + (l & 15);
        Pz[(size_t)m * DO + n] = acc[i][j][r];
      }
    }
  }
  __syncthreads();
}

__global__ __launch_bounds__(256, 4)
void mega(const float* __restrict__ sbj, const float* __restrict__ obj,
          const float* __restrict__ W1, const float* __restrict__ b1,
          const float* __restrict__ W2, const float* __restrict__ b2,
          const float* __restrict__ labs, float* __restrict__ scores,
          char* __restrict__ ws) {
  __shared__ __align__(16) char smem[SMEM_BYTES];
  const int bid = blockIdx.x, tid = threadIdx.x;
  cg::grid_group grid = cg::this_grid();

  unsigned short* Abf = (unsigned short*)(ws);                 // 8 MB  [1024][4096]
  unsigned short* W1t = (unsigned short*)(ws + (8ull << 20));  // 8 MB  [1024][4096]
  unsigned short* W2t = (unsigned short*)(ws + (16ull << 20)); // 2 MB  [1024][1024]
  unsigned short* H   = (unsigned short*)(ws + (18ull << 20)); // 2 MB  [1024][1024]
  float* P  = (float*)(ws + (24ull << 20));                    // 16 MB [4][1024][1024]
  float* SP = (float*)(ws + (40ull << 20));                    // 8 MB  [16][1024][128]

  // ---- P0: prep. Units: 2048 concat + 2048 W1-transpose + 512 W2-transpose ----
  #pragma unroll
  for (int u = 0; u < 5; ++u) {
    const int unit = u * 1024 + bid;
    if (unit < 2048) {
      const int t = unit * 256 + tid;
      const int m = t >> 9;
      const int k = (t & 511) << 3;
      const float* src = (k < DH) ? sbj + (size_t)m * DH + k
                                  : obj + (size_t)m * DH + (k - DH);
      const float4 a = ((const float4*)src)[0];
      const float4 b = ((const float4*)src)[1];
      uint4 o;
      o.x = (unsigned)f2bf(fmaxf(a.x, 0.f)) | ((unsigned)f2bf(fmaxf(a.y, 0.f)) << 16);
      o.y = (unsigned)f2bf(fmaxf(a.z, 0.f)) | ((unsigned)f2bf(fmaxf(a.w, 0.f)) << 16);
      o.z = (unsigned)f2bf(fmaxf(b.x, 0.f)) | ((unsigned)f2bf(fmaxf(b.y, 0.f)) << 16);
      o.w = (unsigned)f2bf(fmaxf(b.z, 0.f)) | ((unsigned)f2bf(fmaxf(b.w, 0.f)) << 16);
      *(uint4*)&Abf[(size_t)m * K1 + k] = o;
    } else if (unit < 4608) {
      // transpose 32(r) x 64(c) fp32 tile -> bf16 out[c][r]
      float (*tl)[65] = (float (*)[65])smem;  // 32x65 f32 = 8.3 KB
      const int tu = unit - 2048;
      const float* in; unsigned short* out; int R, rt, ct;
      if (tu < 2048) { in = W1; out = W1t; R = K1; rt = tu >> 4; ct = tu & 15; }
      else           { in = W2; out = W2t; R = DO; rt = (tu - 2048) >> 4; ct = (tu - 2048) & 15; }
      const int r0 = rt * 32, c0 = ct * 64;
      #pragma unroll
      for (int i = 0; i < 2; ++i) {   // load 32x64: 512 float4 slots
        const int s = i * 256 + tid, rr = s >> 4, cq = s & 15;
        const float4 v = *(const float4*)&in[(size_t)(r0 + rr) * DO + c0 + cq * 4];
        tl[rr][cq * 4 + 0] = v.x; tl[rr][cq * 4 + 1] = v.y;
        tl[rr][cq * 4 + 2] = v.z; tl[rr][cq * 4 + 3] = v.w;
      }
      __syncthreads();
      #pragma unroll
      for (int i = 0; i < 2; ++i) {   // store 64x32: 512 uint2 slots
        const int s = i * 256 + tid, cr = s >> 3, rq = s & 7;
        uint2 o;
        o.x = (unsigned)f2bf(tl[rq * 4 + 0][cr]) | ((unsigned)f2bf(tl[rq * 4 + 1][cr]) << 16);
        o.y = (unsigned)f2bf(tl[rq * 4 + 2][cr]) | ((unsigned)f2bf(tl[rq * 4 + 3][cr]) << 16);
        *(uint2*)&out[(size_t)(c0 + cr) * R + r0 + rq * 4] = o;
      }
      __syncthreads();  // tl reused next unit
    }
  }
  grid.sync();

  // ---- P1: gemm1 (K=4096, split-K=4, KSLICE=1024) -> P ----
  gemm_phase(Abf, W1t, P, K1, 1024, smem, bid, tid);
  grid.sync();

  // ---- P2: combine1  H = relu(sum_z P + b1) -> bf16 ----
  {
    const size_t i4 = (size_t)bid * 256 + tid;
    f32x4 s = ((const f32x4*)P)[i4];
    #pragma unroll
    for (int c = 1; c < 4; ++c) s += ((const f32x4*)P)[(size_t)c * (MN / 4) + i4];
    s += *(const f32x4*)&b1[tid * 4];
    s[0] = fmaxf(s[0], 0.f); s[1] = fmaxf(s[1], 0.f);
    s[2] = fmaxf(s[2], 0.f); s[3] = fmaxf(s[3], 0.f);
    uint2 o;
    o.x = (unsigned)f2bf(s[0]) | ((unsigned)f2bf(s[1]) << 16);
    o.y = (unsigned)f2bf(s[2]) | ((unsigned)f2bf(s[3]) << 16);
    *(uint2*)&H[(size_t)bid * DO + tid * 4] = o;
  }
  grid.sync();

  // ---- P3: gemm2 (K=1024, split-K=4, KSLICE=256) -> P (overwrites) ----
  gemm_phase(H, W2t, P, DO, 256, smem, bid, tid);
  grid.sync();

  // ---- P4: score partials. Unit = (b-tile of 16, d-chunk of 64); 64x16=1024.
  //      d-chunk processed in two 32-d halves to fit 16 KB LDS; labels bf16. ----
  {
    unsigned short* ls = (unsigned short*)smem;      // [32][132] bf16 = 8.4 KB
    float* es = (float*)(smem + 8448);               // [32][17] f32  = 2.2 KB
    const int bt = bid >> 4, dc = bid & 15;
    const int b0 = bt * 16, d0 = dc * 64;
    const int tb = tid & 7;    // b-pair (16 batch = 8 pairs)
    const int tl = tid >> 3;   // label-quad (128 = 32 quads)
    float acc[2][4] = {};

    #pragma unroll
    for (int h = 0; h < 2; ++h) {
      const int dh = d0 + h * 32;
      #pragma unroll
      for (int i = 0; i < 4; ++i) {  // labels 128x32: 1024 float4 slots
        const int s = i * 256 + tid, lr = s >> 3, dq = s & 7;
        const float4 v = *(const float4*)&labs[(size_t)lr * DO + dh + dq * 4];
        ls[(dq * 4 + 0) * 132 + lr] = f2bf(v.x);
        ls[(dq * 4 + 1) * 132 + lr] = f2bf(v.y);
        ls[(dq * 4 + 2) * 132 + lr] = f2bf(v.z);
        ls[(dq * 4 + 3) * 132 + lr] = f2bf(v.w);
      }
      if (tid < 128) {  // emb 16x32 = sum_z P + b2 (E never materialized)
        const int b = tid >> 3, dq = tid & 7;
        const size_t idx = ((size_t)(b0 + b) * DO + dh + dq * 4) >> 2;
        f32x4 v = ((const f32x4*)P)[idx];
        #pragma unroll
        for (int c = 1; c < 4; ++c) v += ((const f32x4*)P)[(size_t)c * (MN / 4) + idx];
        v += *(const f32x4*)&b2[dh + dq * 4];
        es[(dq * 4 + 0) * 17 + b] = v[0]; es[(dq * 4 + 1) * 17 + b] = v[1];
        es[(dq * 4 + 2) * 17 + b] = v[2]; es[(dq * 4 + 3) * 17 + b] = v[3];
      }
      __syncthreads();

      for (int dd = 0; dd < 32; ++dd) {
        const float e0 = es[dd * 17 + tb * 2 + 0];
        const float e1 = es[dd * 17 + tb * 2 + 1];
        const uint2 lw = *(const uint2*)&ls[dd * 132 + tl * 4];
        float lv[4];
        { union { unsigned u; float f; } c0, c1, c2, c3;
          c0.u = (lw.x & 0xFFFFu) << 16; c1.u = lw.x & 0xFFFF0000u;
          c2.u = (lw.y & 0xFFFFu) << 16; c3.u = lw.y & 0xFFFF0000u;
          lv[0] = c0.f; lv[1] = c1.f; lv[2] = c2.f; lv[3] = c3.f; }
        #pragma unroll
        for (int j = 0; j < 4; ++j) {
          float t0 = fmaxf(lv[j] - e0, 0.f); acc[0][j] = fmaf(t0, t0, acc[0][j]);
          float t1 = fmaxf(lv[j] - e1, 0.f); acc[1][j] = fmaf(t1, t1, acc[1][j]);
        }
      }
      __syncthreads();  // LDS reused by next half
    }

    float* SPz = SP + (size_t)dc * (Bn * NL);
    #pragma unroll
    for (int i = 0; i < 2; ++i) {
      float4 v = {acc[i][0], acc[i][1], acc[i][2], acc[i][3]};
      *(float4*)&SPz[(size_t)(b0 + tb * 2 + i) * NL + tl * 4] = v;
    }
  }
  grid.sync();

  // ---- P5: reduce 16 d-chunks -> scores ----
  if (bid < 128) {
    const size_t i4 = (size_t)bid * 256 + tid;
    f32x4 s = ((const f32x4*)SP)[i4];
    #pragma unroll
    for (int c = 1; c < 16; ++c) s += ((const f32x4*)SP)[(size_t)c * 32768 + i4];
    f32x4 o = {-sqrtf(s[0]), -sqrtf(s[1]), -sqrtf(s[2]), -sqrtf(s[3])};
    ((f32x4*)scores)[i4] = o;
  }
}

// ============================================================================
// FALLBACK PATH — verbatim round-7 kernels (proven 141 us) if coop launch fails
// ============================================================================
__global__ __launch_bounds__(256)
void prep(const float* __restrict__ sbj, const float* __restrict__ obj,
          const float* __restrict__ W1, const float* __restrict__ W2,
          unsigned short* __restrict__ Abf,
          unsigned short* __restrict__ W1t, unsigned short* __restrict__ W2t) {
  const int tid = threadIdx.x;
  if (blockIdx.x < 2048) {
    const int t = blockIdx.x * 256 + tid;
    const int m = t >> 9;
    const int k = (t & 511) << 3;
    const float* src = (k < DH) ? sbj + (size_t)m * DH + k
                                : obj + (size_t)m * DH + (k - DH);
    const float4 a = ((const float4*)src)[0];
    const float4 b = ((const float4*)src)[1];
    uint4 o;
    o.x = (unsigned)f2bf(fmaxf(a.x, 0.f)) | ((unsigned)f2bf(fmaxf(a.y, 0.f)) << 16);
    o.y = (unsigned)f2bf(fmaxf(a.z, 0.f)) | ((unsigned)f2bf(fmaxf(a.w, 0.f)) << 16);
    o.z = (unsigned)f2bf(fmaxf(b.x, 0.f)) | ((unsigned)f2bf(fmaxf(b.y, 0.f)) << 16);
    o.w = (unsigned)f2bf(fmaxf(b.z, 0.f)) | ((unsigned)f2bf(fmaxf(b.w, 0.f)) << 16);
    *(uint4*)&Abf[(size_t)m * K1 + k] = o;
    return;
  }
  __shared__ float tl[64][65];
  const int tb = blockIdx.x - 2048;
  int by = tb >> 4;
  const int c0 = (tb & 15) * 64;
  const float* in; unsigned short* out; int R;
  if (by < 64) { in = W1; out = W1t; R = K1; }
  else         { in = W2; out = W2t; R = DO; by -= 64; }
  const int r0 = by * 64;
  {
    const int rr = tid >> 4, cc = (tid & 15) * 4;
    #pragma unroll
    for (int i = 0; i < 4; ++i) {
      const float4 v = *(const float4*)&in[(size_t)(r0 + rr + i * 16) * DO + c0 + cc];
      tl[rr + i * 16][cc + 0] = v.x; tl[rr + i * 16][cc + 1] = v.y;
      tl[rr + i * 16][cc + 2] = v.z; tl[rr + i * 16][cc + 3] = v.w;
    }
  }
  __syncthreads();
  {
    const int r4 = (tid & 15) * 4;
    #pragma unroll
    for (int i = 0; i < 4; ++i) {
      const int cr = i * 16 + (tid >> 4);
      uint2 o;
      o.x = (unsigned)f2bf(tl[r4 + 0][cr]) | ((unsigned)f2bf(tl[r4 + 1][cr]) << 16);
      o.y = (unsigned)f2bf(tl[r4 + 2][cr]) | ((unsigned)f2bf(tl[r4 + 3][cr]) << 16);
      *(uint2*)&out[(size_t)(c0 + cr) * R + r0 + r4] = o;
    }
  }
}

template <int KSLICE>
__global__ __launch_bounds__(256, 4)
void mfma_gemm(const unsigned short* __restrict__ A,
               const unsigned short* __restrict__ Bt,
               float* __restrict__ P, int K) {
  __shared__ __align__(16) unsigned short smem[2 * 64 * 128];
  unsigned short* LA = smem;
  unsigned short* LB = smem + 64 * 128;

  const int tid = threadIdx.x;
  const int w = tid >> 6, l = tid & 63;
  const int bid = blockIdx.x;
  const int g = bid & 7, t = bid >> 3;
  const int x = (g & 3) * 4 + (t & 3);
  const int y = (g >> 2) * 8 + ((t >> 2) & 7);
  const int z = t >> 5;
  const int m0 = y * 64, n0 = x * 64;
  const int kb = z * KSLICE;

  f32x4 acc[4][4] = {};

  constexpr int NIT = KSLICE / 128;
  for (int it = 0; it < NIT; ++it) {
    const int k0 = kb + it * 128;
    #pragma unroll
    for (int i = 0; i < 4; ++i) {
      const int c = i * 256 + tid, m = c >> 4, kc = c & 15;
      const int kcg = (kc & 8) | ((kc & 7) ^ (m & 7));
      __builtin_amdgcn_global_load_lds(
          (const __attribute__((address_space(1))) unsigned int*)(A + (size_t)(m0 + m) * K + k0 + kcg * 8),
          (__attribute__((address_space(3))) unsigned int*)&LA[c * 8], 16, 0, 0);
    }
    #pragma unroll
    for (int i = 0; i < 4; ++i) {
      const int c = i * 256 + tid, n = c >> 4, kc = c & 15;
      const int kcg = (kc & 8) | ((kc & 7) ^ (n & 7));
      __builtin_amdgcn_global_load_lds(
          (const __attribute__((address_space(1))) unsigned int*)(Bt + (size_t)(n0 + n) * K + k0 + kcg * 8),
          (__attribute__((address_space(3))) unsigned int*)&LB[c * 8], 16, 0, 0);
    }
    __syncthreads();

    const int kcq = w * 4 + (l >> 4);
    bf16x8 af[4], bfr[4];
    #pragma unroll
    for (int i = 0; i < 4; ++i) {
      const int r = i * 16 + (l & 15);
      const int kca = (kcq & 8) | ((kcq & 7) ^ (r & 7));
      af[i]  = __builtin_bit_cast(bf16x8, *(const s16x8*)&LA[(r * 16 + kca) * 8]);
      bfr[i] = __builtin_bit_cast(bf16x8, *(const s16x8*)&LB[(r * 16 + kca) * 8]);
    }
    #pragma unroll
    for (int i = 0; i < 4; ++i)
      #pragma unroll
      for (int j = 0; j < 4; ++j)
        acc[i][j] = __builtin_amdgcn_mfma_f32_16x16x32_bf16(af[i], bfr[j], acc[i][j], 0, 0, 0);
    __syncthreads();
  }

  float* red = (float*)smem;
  if (w >= 2) {
    #pragma unroll
    for (int i = 0; i < 4; ++i)
      #pragma unroll
      for (int j = 0; j < 4; ++j)
        *(f32x4*)&red[(w - 2) * 4096 + ((i * 4 + j) * 64 + l) * 4] = acc[i][j];
  }
  __syncthreads();
  if (w < 2) {
    #pragma unroll
    for (int i = 0; i < 4; ++i)
      #pragma unroll
      for (int j = 0; j < 4; ++j)
        acc[i][j] += *(const f32x4*)&red[w * 4096 + ((i * 4 + j) * 64 + l) * 4];
  }
  __syncthreads();
  if (w == 1) {
    #pragma unroll
    for (int i = 0; i < 2; ++i)
      #pragma unroll
      for (int j = 0; j < 4; ++j)
        *(f32x4*)&red[((i * 4 + j) * 64 + l) * 4] = acc[i][j];
  } else if (w == 0) {
    #pragma unroll
    for (int i = 0; i < 2; ++i)
      #pragma unroll
      for (int j = 0; j < 4; ++j)
        *(f32x4*)&red[2048 + ((i * 4 + j) * 64 + l) * 4] = acc[i + 2][j];
  }
  __syncthreads();
  if (w >= 2) return;

  float* Pz = P + (size_t)z * MN;
  if (w == 0) {
    #pragma unroll
    for (int i = 0; i < 2; ++i) {
      #pragma unroll
      for (int j = 0; j < 4; ++j)
        acc[i][j] += *(const f32x4*)&red[((i * 4 + j) * 64 + l) * 4];
      #pragma unroll
      for (int r = 0; r < 4; ++r) {
        const int m = m0 + i * 16 + (l >> 4) * 4 + r;
        #pragma unroll
        for (int j = 0; j < 4; ++j)
          Pz[(size_t)m * DO + n0 + j * 16 + (l & 15)] = acc[i][j][r];
      }
    }
  } else {
    #pragma unroll
    for (int i = 0; i < 2; ++i) {
      #pragma unroll
      for (int j = 0; j < 4; ++j)
        acc[i + 2][j] += *(const f32x4*)&red[2048 + ((i * 4 + j) * 64 + l) * 4];
      #pragma unroll
      for (int r = 0; r < 4; ++r) {
        const int m = m0 + (i + 2) * 16 + (l >> 4) * 4 + r;
        #pragma unroll
        for (int j = 0; j < 4; ++j)
          Pz[(size_t)m * DO + n0 + j * 16 + (l & 15)] = acc[i + 2][j][r];
      }
    }
  }
}

template <int KS, bool RELU, bool OUT_BF16>
__global__ __launch_bounds__(256)
void combine(const float* __restrict__ P, const float* __restrict__ bias,
             void* __restrict__ out) {
  const int row = blockIdx.x, t = threadIdx.x;
  const size_t i4 = (size_t)row * 256 + t;
  f32x4 s = ((const f32x4*)P)[i4];
  #pragma unroll
  for (int c = 1; c < KS; ++c) s += ((const f32x4*)P)[(size_t)c * (MN / 4) + i4];
  const f32x4 bb = *(const f32x4*)&bias[t * 4];
  s += bb;
  if (RELU) {
    s[0] = fmaxf(s[0], 0.f); s[1] = fmaxf(s[1], 0.f);
    s[2] = fmaxf(s[2], 0.f); s[3] = fmaxf(s[3], 0.f);
  }
  if (OUT_BF16) {
    uint2 o;
    o.x = (unsigned)f2bf(s[0]) | ((unsigned)f2bf(s[1]) << 16);
    o.y = (unsigned)f2bf(s[2]) | ((unsigned)f2bf(s[3]) << 16);
    *(uint2*)((unsigned short*)out + (size_t)row * DO + t * 4) = o;
  } else {
    *(f32x4*)((float*)out + (size_t)row * DO + t * 4) = s;
  }
}

__global__ __launch_bounds__(256)
void score_partial(const float* __restrict__ P, const float* __restrict__ b2,
                   const float* __restrict__ labels, float* __restrict__ SP) {
  __shared__ float es[64][33];
  __shared__ float ls[64][132];
  const int tid = threadIdx.x;
  const int b0 = blockIdx.x * 32;
  const int d0 = blockIdx.y * 64;

  #pragma unroll
  for (int i = 0; i < 2; ++i) {
    const int fi = tid + i * 256;
    const int b = fi >> 4, dq = fi & 15;
    const size_t idx = ((size_t)(b0 + b) * DO + d0 + dq * 4) / 4;
    f32x4 v = ((const f32x4*)P)[idx];
    #pragma unroll
    for (int c = 1; c < 4; ++c) v += ((const f32x4*)P)[(size_t)c * (MN / 4) + idx];
    v += *(const f32x4*)&b2[d0 + dq * 4];
    es[dq * 4 + 0][b] = v[0]; es[dq * 4 + 1][b] = v[1];
    es[dq * 4 + 2][b] = v[2]; es[dq * 4 + 3][b] = v[3];
  }
  #pragma unroll
  for (int i = 0; i < 8; ++i) {
    const int fi = tid + i * 256;
    const int lr = fi >> 4, dq = fi & 15;
    const float4 v = *(const float4*)&labels[(size_t)lr * DO + d0 + dq * 4];
    ls[dq * 4 + 0][lr] = v.x; ls[dq * 4 + 1][lr] = v.y;
    ls[dq * 4 + 2][lr] = v.z; ls[dq * 4 + 3][lr] = v.w;
  }
  __syncthreads();

  const int tb = tid & 15;
  const int tl = tid >> 4;
  float acc[2][8] = {};

  for (int dd = 0; dd < 64; ++dd) {
    const float e0 = es[dd][tb * 2 + 0];
    const float e1 = es[dd][tb * 2 + 1];
    const float4 l0 = *(const float4*)&ls[dd][tl * 8];
    const float4 l1 = *(const float4*)&ls[dd][tl * 8 + 4];
    const float lv[8] = {l0.x, l0.y, l0.z, l0.w, l1.x, l1.y, l1.z, l1.w};
    #pragma unroll
    for (int j = 0; j < 8; ++j) {
      float t0 = fmaxf(lv[j] - e0, 0.f); acc[0][j] = fmaf(t0, t0, acc[0][j]);
      float t1 = fmaxf(lv[j] - e1, 0.f); acc[1][j] = fmaf(t1, t1, acc[1][j]);
    }
  }

  float* SPz = SP + (size_t)blockIdx.y * (Bn * NL);
  #pragma unroll
  for (int i = 0; i < 2; ++i) {
    const size_t base = (size_t)(b0 + tb * 2 + i) * NL + tl * 8;
    float4 v0 = {acc[i][0], acc[i][1], acc[i][2], acc[i][3]};
    float4 v1 = {acc[i][4], acc[i][5], acc[i][6], acc[i][7]};
    *(float4*)&SPz[base]     = v0;
    *(float4*)&SPz[base + 4] = v1;
  }
}

__global__ __launch_bounds__(256)
void score_reduce(const float* __restrict__ SP, float* __restrict__ out) {
  const size_t i4 = (size_t)blockIdx.x * 256 + threadIdx.x;
  f32x4 s = ((const f32x4*)SP)[i4];
  #pragma unroll
  for (int c = 1; c < 16; ++c) s += ((const f32x4*)SP)[(size_t)c * 32768 + i4];
  f32x4 o = {-sqrtf(s[0]), -sqrtf(s[1]), -sqrtf(s[2]), -sqrtf(s[3])};
  ((f32x4*)out)[i4] = o;
}

extern "C" void kernel_launch(void* const* d_in, const int* in_sizes, int n_in,
                              void* d_out, int out_size, void* d_ws, size_t ws_size,
                              hipStream_t stream) {
  const float* sbj  = (const float*)d_in[0];
  const float* obj  = (const float*)d_in[1];
  const float* W1   = (const float*)d_in[2];
  const float* b1   = (const float*)d_in[3];
  const float* W2   = (const float*)d_in[4];
  const float* b2   = (const float*)d_in[5];
  const float* labs = (const float*)d_in[6];
  float* scores = (float*)d_out;
  char* ws = (char*)d_ws;

  void* args[] = {(void*)&sbj, (void*)&obj, (void*)&W1, (void*)&b1,
                  (void*)&W2,  (void*)&b2,  (void*)&labs, (void*)&scores,
                  (void*)&ws};
  hipError_t err = hipLaunchCooperativeKernel((const void*)mega, dim3(1024),
                                              dim3(256), args, 0, stream);
  if (err == hipSuccess) return;

  // ---- fallback: proven round-7 multi-kernel path ----
  unsigned short* Abf = (unsigned short*)(ws);
  unsigned short* W1t = (unsigned short*)(ws + (8ull << 20));
  unsigned short* W2t = (unsigned short*)(ws + (16ull << 20));
  unsigned short* H   = (unsigned short*)(ws + (18ull << 20));
  float* P  = (float*)(ws + (24ull << 20));
  float* SP = (float*)(ws + (40ull << 20));

  dim3 blk(256);
  prep<<<dim3(2048 + 1280), blk, 0, stream>>>(sbj, obj, W1, W2, Abf, W1t, W2t);
  mfma_gemm<1024><<<dim3(1024), blk, 0, stream>>>(Abf, W1t, P, K1);
  combine<4, true, true><<<dim3(Bn), blk, 0, stream>>>(P, b1, H);
  mfma_gemm<256><<<dim3(1024), blk, 0, stream>>>(H, W2t, P, DO);
  score_partial<<<dim3(32, 16), blk, 0, stream>>>(P, b2, labs, SP);
  score_reduce<<<dim3(128), blk, 0, stream>>>(SP, scores);
}

// Round 10
// 146.881 us; speedup vs baseline: 4.9146x; 4.9146x over previous
//
#include <hip/hip_runtime.h>
#include <math.h>

constexpr int Bn = 1024, DH = 2048, K1 = 4096, DO = 1024, NL = 128;
constexpr int MN = Bn * DO;  // 1M elements

typedef __bf16 bf16x8 __attribute__((ext_vector_type(8)));
typedef short  s16x8  __attribute__((ext_vector_type(8)));
typedef float  f32x4  __attribute__((ext_vector_type(4)));

__device__ __forceinline__ unsigned short f2bf(float f) {
  union { float f; unsigned u; } v; v.f = f;
  unsigned r = v.u + 0x7FFFu + ((v.u >> 16) & 1u);  // RNE
  return (unsigned short)(r >> 16);
}

// ---------- prep: concat+relu+bf16 (blocks 0..2047) + W1/W2 transposes ----------
__global__ __launch_bounds__(256)
void prep(const float* __restrict__ sbj, const float* __restrict__ obj,
          const float* __restrict__ W1, const float* __restrict__ W2,
          unsigned short* __restrict__ Abf,
          unsigned short* __restrict__ W1t, unsigned short* __restrict__ W2t) {
  const int tid = threadIdx.x;
  if (blockIdx.x < 2048) {
    const int t = blockIdx.x * 256 + tid;
    const int m = t >> 9;
    const int k = (t & 511) << 3;
    const float* src = (k < DH) ? sbj + (size_t)m * DH + k
                                : obj + (size_t)m * DH + (k - DH);
    const float4 a = ((const float4*)src)[0];
    const float4 b = ((const float4*)src)[1];
    uint4 o;
    o.x = (unsigned)f2bf(fmaxf(a.x, 0.f)) | ((unsigned)f2bf(fmaxf(a.y, 0.f)) << 16);
    o.y = (unsigned)f2bf(fmaxf(a.z, 0.f)) | ((unsigned)f2bf(fmaxf(a.w, 0.f)) << 16);
    o.z = (unsigned)f2bf(fmaxf(b.x, 0.f)) | ((unsigned)f2bf(fmaxf(b.y, 0.f)) << 16);
    o.w = (unsigned)f2bf(fmaxf(b.z, 0.f)) | ((unsigned)f2bf(fmaxf(b.w, 0.f)) << 16);
    *(uint4*)&Abf[(size_t)m * K1 + k] = o;
    return;
  }
  __shared__ float tl[64][65];
  const int tb = blockIdx.x - 2048;
  int by = tb >> 4;
  const int c0 = (tb & 15) * 64;
  const float* in; unsigned short* out; int R;
  if (by < 64) { in = W1; out = W1t; R = K1; }
  else         { in = W2; out = W2t; R = DO; by -= 64; }
  const int r0 = by * 64;
  {
    const int rr = tid >> 4, cc = (tid & 15) * 4;
    #pragma unroll
    for (int i = 0; i < 4; ++i) {
      const float4 v = *(const float4*)&in[(size_t)(r0 + rr + i * 16) * DO + c0 + cc];
      tl[rr + i * 16][cc + 0] = v.x; tl[rr + i * 16][cc + 1] = v.y;
      tl[rr + i * 16][cc + 2] = v.z; tl[rr + i * 16][cc + 3] = v.w;
    }
  }
  __syncthreads();
  {
    const int r4 = (tid & 15) * 4;
    #pragma unroll
    for (int i = 0; i < 4; ++i) {
      const int cr = i * 16 + (tid >> 4);
      uint2 o;
      o.x = (unsigned)f2bf(tl[r4 + 0][cr]) | ((unsigned)f2bf(tl[r4 + 1][cr]) << 16);
      o.y = (unsigned)f2bf(tl[r4 + 2][cr]) | ((unsigned)f2bf(tl[r4 + 3][cr]) << 16);
      *(uint2*)&out[(size_t)(c0 + cr) * R + r0 + r4] = o;
    }
  }
}

// ---------- MFMA GEMM: 128x128 tile, 4 waves in 2x2 (64x64 quadrant each,
// no LDS reduce), BK=64 (LDS 32 KB), split-K=8 with z = XCD (bid&7):
// each XCD owns one full k-slice -> A+B slice (2 MB) L2-resident.
// Writes fp32 partials P[z][1024][1024]. All acc indexing compile-time. ----------
template <int KSLICE>
__global__ __launch_bounds__(256, 2)
void mfma_gemm(const unsigned short* __restrict__ A,
               const unsigned short* __restrict__ Bt,
               float* __restrict__ P, int K) {
  __shared__ __align__(16) unsigned short smem[2 * 128 * 64];  // 32 KB
  unsigned short* LA = smem;            // [128 rows][8 chunks x 8 bf16] = 16 KB
  unsigned short* LB = smem + 128 * 64; // 16 KB

  const int tid = threadIdx.x;
  const int w = tid >> 6, l = tid & 63;
  // bid = z + 8*t ; z = XCD = k-slice, t = 0..63 -> x = t&7, y = t>>3
  const int bid = blockIdx.x;
  const int z = bid & 7, t = bid >> 3;
  const int m0 = (t >> 3) * 128, n0 = (t & 7) * 128;
  const int kb = z * KSLICE;

  f32x4 acc[4][4] = {};

  constexpr int NIT = KSLICE / 64;
  for (int it = 0; it < NIT; ++it) {
    const int k0 = kb + it * 64;
    // stage A,B: 1024 slots each (row 0..127, chunk 0..7), 4 DMA/thread each
    #pragma unroll
    for (int i = 0; i < 4; ++i) {
      const int c = i * 256 + tid, row = c >> 3, kc = c & 7;
      const int kcg = kc ^ (row & 7);
      __builtin_amdgcn_global_load_lds(
          (const __attribute__((address_space(1))) unsigned int*)(A + (size_t)(m0 + row) * K + k0 + kcg * 8),
          (__attribute__((address_space(3))) unsigned int*)&LA[c * 8], 16, 0, 0);
    }
    #pragma unroll
    for (int i = 0; i < 4; ++i) {
      const int c = i * 256 + tid, row = c >> 3, kc = c & 7;
      const int kcg = kc ^ (row & 7);
      __builtin_amdgcn_global_load_lds(
          (const __attribute__((address_space(1))) unsigned int*)(Bt + (size_t)(n0 + row) * K + k0 + kcg * 8),
          (__attribute__((address_space(3))) unsigned int*)&LB[c * 8], 16, 0, 0);
    }
    __syncthreads();

    #pragma unroll
    for (int s = 0; s < 2; ++s) {  // two 32-k MFMA steps cover BK=64
      const int kcq = s * 4 + (l >> 4);  // logical chunk 0..7
      bf16x8 af[4], bfr[4];
      #pragma unroll
      for (int i = 0; i < 4; ++i) {
        const int r = (w >> 1) * 64 + i * 16 + (l & 15);
        const int kca = kcq ^ (r & 7);
        af[i] = __builtin_bit_cast(bf16x8, *(const s16x8*)&LA[(r * 8 + kca) * 8]);
      }
      #pragma unroll
      for (int j = 0; j < 4; ++j) {
        const int rr = (w & 1) * 64 + j * 16 + (l & 15);
        const int kcb = kcq ^ (rr & 7);
        bfr[j] = __builtin_bit_cast(bf16x8, *(const s16x8*)&LB[(rr * 8 + kcb) * 8]);
      }
      #pragma unroll
      for (int i = 0; i < 4; ++i)
        #pragma unroll
        for (int j = 0; j < 4; ++j)
          acc[i][j] = __builtin_amdgcn_mfma_f32_16x16x32_bf16(af[i], bfr[j], acc[i][j], 0, 0, 0);
    }
    __syncthreads();
  }

  // store quadrant partials (C/D: col=l&15 -> n, row=(l>>4)*4+r -> m)
  float* Pz = P + (size_t)z * MN;
  #pragma unroll
  for (int i = 0; i < 4; ++i) {
    #pragma unroll
    for (int r = 0; r < 4; ++r) {
      const int m = m0 + (w >> 1) * 64 + i * 16 + (l >> 4) * 4 + r;
      #pragma unroll
      for (int j = 0; j < 4; ++j) {
        const int n = n0 + (w & 1) * 64 + j * 16 + (l & 15);
        Pz[(size_t)m * DO + n] = acc[i][j][r];
      }
    }
  }
}

// ---------- combine: out = act(sum_z P[z] + bias) ----------
template <int KS, bool RELU, bool OUT_BF16>
__global__ __launch_bounds__(256)
void combine(const float* __restrict__ P, const float* __restrict__ bias,
             void* __restrict__ out) {
  const int row = blockIdx.x, t = threadIdx.x;
  const size_t i4 = (size_t)row * 256 + t;
  f32x4 s = ((const f32x4*)P)[i4];
  #pragma unroll
  for (int c = 1; c < KS; ++c) s += ((const f32x4*)P)[(size_t)c * (MN / 4) + i4];
  const f32x4 bb = *(const f32x4*)&bias[t * 4];
  s += bb;
  if (RELU) {
    s[0] = fmaxf(s[0], 0.f); s[1] = fmaxf(s[1], 0.f);
    s[2] = fmaxf(s[2], 0.f); s[3] = fmaxf(s[3], 0.f);
  }
  if (OUT_BF16) {
    uint2 o;
    o.x = (unsigned)f2bf(s[0]) | ((unsigned)f2bf(s[1]) << 16);
    o.y = (unsigned)f2bf(s[2]) | ((unsigned)f2bf(s[3]) << 16);
    *(uint2*)((unsigned short*)out + (size_t)row * DO + t * 4) = o;
  } else {
    *(f32x4*)((float*)out + (size_t)row * DO + t * 4) = s;
  }
}

// ---------- scores: fused (sum_z P + b2) staging + d-split partials ----------
__global__ __launch_bounds__(256)
void score_partial(const float* __restrict__ P, const float* __restrict__ b2,
                   const float* __restrict__ labels, float* __restrict__ SP) {
  __shared__ float es[64][33];   // [d][b]
  __shared__ float ls[64][132];  // [d][l]
  const int tid = threadIdx.x;
  const int b0 = blockIdx.x * 32;
  const int d0 = blockIdx.y * 64;

  // stage emb chunk = sum of 8 gemm2 partials + bias (E never materialized)
  #pragma unroll
  for (int i = 0; i < 2; ++i) {
    const int fi = tid + i * 256;
    const int b = fi >> 4, dq = fi & 15;
    const size_t idx = ((size_t)(b0 + b) * DO + d0 + dq * 4) / 4;
    f32x4 v = ((const f32x4*)P)[idx];
    #pragma unroll
    for (int c = 1; c < 8; ++c) v += ((const f32x4*)P)[(size_t)c * (MN / 4) + idx];
    v += *(const f32x4*)&b2[d0 + dq * 4];
    es[dq * 4 + 0][b] = v[0]; es[dq * 4 + 1][b] = v[1];
    es[dq * 4 + 2][b] = v[2]; es[dq * 4 + 3][b] = v[3];
  }
  #pragma unroll
  for (int i = 0; i < 8; ++i) {
    const int fi = tid + i * 256;
    const int lr = fi >> 4, dq = fi & 15;
    const float4 v = *(const float4*)&labels[(size_t)lr * DO + d0 + dq * 4];
    ls[dq * 4 + 0][lr] = v.x; ls[dq * 4 + 1][lr] = v.y;
    ls[dq * 4 + 2][lr] = v.z; ls[dq * 4 + 3][lr] = v.w;
  }
  __syncthreads();

  const int tb = tid & 15;   // b-pair
  const int tl = tid >> 4;   // label-octet
  float acc[2][8] = {};

  for (int dd = 0; dd < 64; ++dd) {
    const float e0 = es[dd][tb * 2 + 0];
    const float e1 = es[dd][tb * 2 + 1];
    const float4 l0 = *(const float4*)&ls[dd][tl * 8];
    const float4 l1 = *(const float4*)&ls[dd][tl * 8 + 4];
    const float lv[8] = {l0.x, l0.y, l0.z, l0.w, l1.x, l1.y, l1.z, l1.w};
    #pragma unroll
    for (int j = 0; j < 8; ++j) {
      float t0 = fmaxf(lv[j] - e0, 0.f); acc[0][j] = fmaf(t0, t0, acc[0][j]);
      float t1 = fmaxf(lv[j] - e1, 0.f); acc[1][j] = fmaf(t1, t1, acc[1][j]);
    }
  }

  float* SPz = SP + (size_t)blockIdx.y * (Bn * NL);
  #pragma unroll
  for (int i = 0; i < 2; ++i) {
    const size_t base = (size_t)(b0 + tb * 2 + i) * NL + tl * 8;
    float4 v0 = {acc[i][0], acc[i][1], acc[i][2], acc[i][3]};
    float4 v1 = {acc[i][4], acc[i][5], acc[i][6], acc[i][7]};
    *(float4*)&SPz[base]     = v0;
    *(float4*)&SPz[base + 4] = v1;
  }
}

__global__ __launch_bounds__(256)
void score_reduce(const float* __restrict__ SP, float* __restrict__ out) {
  const size_t i4 = (size_t)blockIdx.x * 256 + threadIdx.x;
  f32x4 s = ((const f32x4*)SP)[i4];
  #pragma unroll
  for (int c = 1; c < 16; ++c) s += ((const f32x4*)SP)[(size_t)c * 32768 + i4];
  f32x4 o = {-sqrtf(s[0]), -sqrtf(s[1]), -sqrtf(s[2]), -sqrtf(s[3])};
  ((f32x4*)out)[i4] = o;
}

extern "C" void kernel_launch(void* const* d_in, const int* in_sizes, int n_in,
                              void* d_out, int out_size, void* d_ws, size_t ws_size,
                              hipStream_t stream) {
  const float* sbj  = (const float*)d_in[0];
  const float* obj  = (const float*)d_in[1];
  const float* W1   = (const float*)d_in[2];
  const float* b1   = (const float*)d_in[3];
  const float* W2   = (const float*)d_in[4];
  const float* b2   = (const float*)d_in[5];
  const float* labs = (const float*)d_in[6];
  float* scores = (float*)d_out;
  char* ws = (char*)d_ws;

  // Layout (MB, ws = 256 MB): Abf [0,8)  W1t [8,16)  W2t [16,18)  H [18,20)
  //                           P [24,56) = 8 x 4 MB    SP [56,64)
  unsigned short* Abf = (unsigned short*)(ws);
  unsigned short* W1t = (unsigned short*)(ws + (8ull << 20));
  unsigned short* W2t = (unsigned short*)(ws + (16ull << 20));
  unsigned short* H   = (unsigned short*)(ws + (18ull << 20));
  float* P  = (float*)(ws + (24ull << 20));
  float* SP = (float*)(ws + (56ull << 20));

  dim3 blk(256);
  prep<<<dim3(2048 + 1280), blk, 0, stream>>>(sbj, obj, W1, W2, Abf, W1t, W2t);

  // GEMM1: K=4096, 128^2 tiles, split-K=8 (KSLICE=512) -> 512 blocks, z = XCD
  mfma_gemm<512><<<dim3(512), blk, 0, stream>>>(Abf, W1t, P, K1);
  combine<8, true, true><<<dim3(Bn), blk, 0, stream>>>(P, b1, H);
  // GEMM2: K=1024, 128^2 tiles, split-K=8 (KSLICE=128) -> 512 blocks
  mfma_gemm<128><<<dim3(512), blk, 0, stream>>>(H, W2t, P, DO);
  // score: fused 8-slice z-sum + b2 bias in staging; then d-chunk reduce
  score_partial<<<dim3(32, 16), blk, 0, stream>>>(P, b2, labs, SP);
  score_reduce<<<dim3(128), blk, 0, stream>>>(SP, scores);
}

// Round 11
// 136.462 us; speedup vs baseline: 5.2898x; 1.0764x over previous
//
#include <hip/hip_runtime.h>
#include <math.h>

constexpr int Bn = 1024, DH = 2048, K1 = 4096, DO = 1024, NL = 128;
constexpr int MN = Bn * DO;  // 1M elements

typedef __bf16 bf16x8 __attribute__((ext_vector_type(8)));
typedef short  s16x8  __attribute__((ext_vector_type(8)));
typedef float  f32x4  __attribute__((ext_vector_type(4)));

__device__ __forceinline__ unsigned short f2bf(float f) {
  union { float f; unsigned u; } v; v.f = f;
  unsigned r = v.u + 0x7FFFu + ((v.u >> 16) & 1u);  // RNE
  return (unsigned short)(r >> 16);
}

// ---------- prep: concat+relu+bf16 (blocks 0..2047) + W1/W2 transposes ----------
__global__ __launch_bounds__(256)
void prep(const float* __restrict__ sbj, const float* __restrict__ obj,
          const float* __restrict__ W1, const float* __restrict__ W2,
          unsigned short* __restrict__ Abf,
          unsigned short* __restrict__ W1t, unsigned short* __restrict__ W2t) {
  const int tid = threadIdx.x;
  if (blockIdx.x < 2048) {
    const int t = blockIdx.x * 256 + tid;
    const int m = t >> 9;
    const int k = (t & 511) << 3;
    const float* src = (k < DH) ? sbj + (size_t)m * DH + k
                                : obj + (size_t)m * DH + (k - DH);
    const float4 a = ((const float4*)src)[0];
    const float4 b = ((const float4*)src)[1];
    uint4 o;
    o.x = (unsigned)f2bf(fmaxf(a.x, 0.f)) | ((unsigned)f2bf(fmaxf(a.y, 0.f)) << 16);
    o.y = (unsigned)f2bf(fmaxf(a.z, 0.f)) | ((unsigned)f2bf(fmaxf(a.w, 0.f)) << 16);
    o.z = (unsigned)f2bf(fmaxf(b.x, 0.f)) | ((unsigned)f2bf(fmaxf(b.y, 0.f)) << 16);
    o.w = (unsigned)f2bf(fmaxf(b.z, 0.f)) | ((unsigned)f2bf(fmaxf(b.w, 0.f)) << 16);
    *(uint4*)&Abf[(size_t)m * K1 + k] = o;
    return;
  }
  __shared__ float tl[64][65];
  const int tb = blockIdx.x - 2048;
  int by = tb >> 4;
  const int c0 = (tb & 15) * 64;
  const float* in; unsigned short* out; int R;
  if (by < 64) { in = W1; out = W1t; R = K1; }
  else         { in = W2; out = W2t; R = DO; by -= 64; }
  const int r0 = by * 64;
  {
    const int rr = tid >> 4, cc = (tid & 15) * 4;
    #pragma unroll
    for (int i = 0; i < 4; ++i) {
      const float4 v = *(const float4*)&in[(size_t)(r0 + rr + i * 16) * DO + c0 + cc];
      tl[rr + i * 16][cc + 0] = v.x; tl[rr + i * 16][cc + 1] = v.y;
      tl[rr + i * 16][cc + 2] = v.z; tl[rr + i * 16][cc + 3] = v.w;
    }
  }
  __syncthreads();
  {
    const int r4 = (tid & 15) * 4;
    #pragma unroll
    for (int i = 0; i < 4; ++i) {
      const int cr = i * 16 + (tid >> 4);
      uint2 o;
      o.x = (unsigned)f2bf(tl[r4 + 0][cr]) | ((unsigned)f2bf(tl[r4 + 1][cr]) << 16);
      o.y = (unsigned)f2bf(tl[r4 + 2][cr]) | ((unsigned)f2bf(tl[r4 + 3][cr]) << 16);
      *(uint2*)&out[(size_t)(c0 + cr) * R + r0 + r4] = o;
    }
  }
}

// ---------- GEMM1: 128x128 tile, 4 waves in 2x2 (64x64 quadrant each),
// BK=64, split-K=8 with z = XCD (bid&7): per-XCD slice (2 MB) L2-resident.
// Writes fp32 partials P[z][1024][1024]. ----------
template <int KSLICE>
__global__ __launch_bounds__(256, 2)
void mfma_gemm(const unsigned short* __restrict__ A,
               const unsigned short* __restrict__ Bt,
               float* __restrict__ P, int K) {
  __shared__ __align__(16) unsigned short smem[2 * 128 * 64];  // 32 KB
  unsigned short* LA = smem;
  unsigned short* LB = smem + 128 * 64;

  const int tid = threadIdx.x;
  const int w = tid >> 6, l = tid & 63;
  const int bid = blockIdx.x;
  const int z = bid & 7, t = bid >> 3;
  const int m0 = (t >> 3) * 128, n0 = (t & 7) * 128;
  const int kb = z * KSLICE;

  f32x4 acc[4][4] = {};

  constexpr int NIT = KSLICE / 64;
  for (int it = 0; it < NIT; ++it) {
    const int k0 = kb + it * 64;
    #pragma unroll
    for (int i = 0; i < 4; ++i) {
      const int c = i * 256 + tid, row = c >> 3, kc = c & 7;
      const int kcg = kc ^ (row & 7);
      __builtin_amdgcn_global_load_lds(
          (const __attribute__((address_space(1))) unsigned int*)(A + (size_t)(m0 + row) * K + k0 + kcg * 8),
          (__attribute__((address_space(3))) unsigned int*)&LA[c * 8], 16, 0, 0);
    }
    #pragma unroll
    for (int i = 0; i < 4; ++i) {
      const int c = i * 256 + tid, row = c >> 3, kc = c & 7;
      const int kcg = kc ^ (row & 7);
      __builtin_amdgcn_global_load_lds(
          (const __attribute__((address_space(1))) unsigned int*)(Bt + (size_t)(n0 + row) * K + k0 + kcg * 8),
          (__attribute__((address_space(3))) unsigned int*)&LB[c * 8], 16, 0, 0);
    }
    __syncthreads();

    #pragma unroll
    for (int s = 0; s < 2; ++s) {
      const int kcq = s * 4 + (l >> 4);
      bf16x8 af[4], bfr[4];
      #pragma unroll
      for (int i = 0; i < 4; ++i) {
        const int r = (w >> 1) * 64 + i * 16 + (l & 15);
        const int kca = kcq ^ (r & 7);
        af[i] = __builtin_bit_cast(bf16x8, *(const s16x8*)&LA[(r * 8 + kca) * 8]);
      }
      #pragma unroll
      for (int j = 0; j < 4; ++j) {
        const int rr = (w & 1) * 64 + j * 16 + (l & 15);
        const int kcb = kcq ^ (rr & 7);
        bfr[j] = __builtin_bit_cast(bf16x8, *(const s16x8*)&LB[(rr * 8 + kcb) * 8]);
      }
      #pragma unroll
      for (int i = 0; i < 4; ++i)
        #pragma unroll
        for (int j = 0; j < 4; ++j)
          acc[i][j] = __builtin_amdgcn_mfma_f32_16x16x32_bf16(af[i], bfr[j], acc[i][j], 0, 0, 0);
    }
    __syncthreads();
  }

  float* Pz = P + (size_t)z * MN;
  #pragma unroll
  for (int i = 0; i < 4; ++i) {
    #pragma unroll
    for (int r = 0; r < 4; ++r) {
      const int m = m0 + (w >> 1) * 64 + i * 16 + (l >> 4) * 4 + r;
      #pragma unroll
      for (int j = 0; j < 4; ++j) {
        const int n = n0 + (w & 1) * 64 + j * 16 + (l & 15);
        Pz[(size_t)m * DO + n] = acc[i][j][r];
      }
    }
  }
}

// ---------- combine1: H = relu(sum_z P[z] + b1) -> bf16 ----------
__global__ __launch_bounds__(256)
void combine1(const float* __restrict__ P, const float* __restrict__ bias,
              unsigned short* __restrict__ out) {
  const int row = blockIdx.x, t = threadIdx.x;
  const size_t i4 = (size_t)row * 256 + t;
  f32x4 s = ((const f32x4*)P)[i4];
  #pragma unroll
  for (int c = 1; c < 8; ++c) s += ((const f32x4*)P)[(size_t)c * (MN / 4) + i4];
  s += *(const f32x4*)&bias[t * 4];
  s[0] = fmaxf(s[0], 0.f); s[1] = fmaxf(s[1], 0.f);
  s[2] = fmaxf(s[2], 0.f); s[3] = fmaxf(s[3], 0.f);
  uint2 o;
  o.x = (unsigned)f2bf(s[0]) | ((unsigned)f2bf(s[1]) << 16);
  o.y = (unsigned)f2bf(s[2]) | ((unsigned)f2bf(s[3]) << 16);
  *(uint2*)&out[(size_t)row * DO + t * 4] = o;
}

// ---------- GEMM2 (full-K, no block split): 64x64 tile, in-block 4-wave
// k-split over BK=128 staged (r7-proven), LDS tree-reduce, epilogue writes
// E = sum + b2 directly (fp32). 256 blocks (16x16 tiles). ----------
__global__ __launch_bounds__(256, 4)
void gemm2_full(const unsigned short* __restrict__ A,
                const unsigned short* __restrict__ Bt,
                const float* __restrict__ b2, float* __restrict__ E) {
  __shared__ __align__(16) unsigned short smem[2 * 64 * 128];  // 32 KB
  unsigned short* LA = smem;
  unsigned short* LB = smem + 64 * 128;

  const int tid = threadIdx.x;
  const int w = tid >> 6, l = tid & 63;
  const int bid = blockIdx.x;
  const int m0 = (bid >> 4) * 64, n0 = (bid & 15) * 64;

  f32x4 acc[4][4] = {};

  for (int it = 0; it < 8; ++it) {  // K=1024, BK=128
    const int k0 = it * 128;
    #pragma unroll
    for (int i = 0; i < 4; ++i) {
      const int c = i * 256 + tid, m = c >> 4, kc = c & 15;
      const int kcg = (kc & 8) | ((kc & 7) ^ (m & 7));
      __builtin_amdgcn_global_load_lds(
          (const __attribute__((address_space(1))) unsigned int*)(A + (size_t)(m0 + m) * DO + k0 + kcg * 8),
          (__attribute__((address_space(3))) unsigned int*)&LA[c * 8], 16, 0, 0);
    }
    #pragma unroll
    for (int i = 0; i < 4; ++i) {
      const int c = i * 256 + tid, n = c >> 4, kc = c & 15;
      const int kcg = (kc & 8) | ((kc & 7) ^ (n & 7));
      __builtin_amdgcn_global_load_lds(
          (const __attribute__((address_space(1))) unsigned int*)(Bt + (size_t)(n0 + n) * DO + k0 + kcg * 8),
          (__attribute__((address_space(3))) unsigned int*)&LB[c * 8], 16, 0, 0);
    }
    __syncthreads();

    const int kcq = w * 4 + (l >> 4);
    bf16x8 af[4], bfr[4];
    #pragma unroll
    for (int i = 0; i < 4; ++i) {
      const int r = i * 16 + (l & 15);
      const int kca = (kcq & 8) | ((kcq & 7) ^ (r & 7));
      af[i]  = __builtin_bit_cast(bf16x8, *(const s16x8*)&LA[(r * 16 + kca) * 8]);
      bfr[i] = __builtin_bit_cast(bf16x8, *(const s16x8*)&LB[(r * 16 + kca) * 8]);
    }
    #pragma unroll
    for (int i = 0; i < 4; ++i)
      #pragma unroll
      for (int j = 0; j < 4; ++j)
        acc[i][j] = __builtin_amdgcn_mfma_f32_16x16x32_bf16(af[i], bfr[j], acc[i][j], 0, 0, 0);
    __syncthreads();
  }

  // 4-wave k-split tree reduction (fully unrolled; r7-proven)
  float* red = (float*)smem;
  if (w >= 2) {
    #pragma unroll
    for (int i = 0; i < 4; ++i)
      #pragma unroll
      for (int j = 0; j < 4; ++j)
        *(f32x4*)&red[(w - 2) * 4096 + ((i * 4 + j) * 64 + l) * 4] = acc[i][j];
  }
  __syncthreads();
  if (w < 2) {
    #pragma unroll
    for (int i = 0; i < 4; ++i)
      #pragma unroll
      for (int j = 0; j < 4; ++j)
        acc[i][j] += *(const f32x4*)&red[w * 4096 + ((i * 4 + j) * 64 + l) * 4];
  }
  __syncthreads();
  if (w == 1) {
    #pragma unroll
    for (int i = 0; i < 2; ++i)
      #pragma unroll
      for (int j = 0; j < 4; ++j)
        *(f32x4*)&red[((i * 4 + j) * 64 + l) * 4] = acc[i][j];
  } else if (w == 0) {
    #pragma unroll
    for (int i = 0; i < 2; ++i)
      #pragma unroll
      for (int j = 0; j < 4; ++j)
        *(f32x4*)&red[2048 + ((i * 4 + j) * 64 + l) * 4] = acc[i + 2][j];
  }
  __syncthreads();
  if (w >= 2) return;

  if (w == 0) {
    #pragma unroll
    for (int i = 0; i < 2; ++i) {
      #pragma unroll
      for (int j = 0; j < 4; ++j)
        acc[i][j] += *(const f32x4*)&red[((i * 4 + j) * 64 + l) * 4];
      #pragma unroll
      for (int r = 0; r < 4; ++r) {
        const int m = m0 + i * 16 + (l >> 4) * 4 + r;
        #pragma unroll
        for (int j = 0; j < 4; ++j) {
          const int n = n0 + j * 16 + (l & 15);
          E[(size_t)m * DO + n] = acc[i][j][r] + b2[n];
        }
      }
    }
  } else {
    #pragma unroll
    for (int i = 0; i < 2; ++i) {
      #pragma unroll
      for (int j = 0; j < 4; ++j)
        acc[i + 2][j] += *(const f32x4*)&red[2048 + ((i * 4 + j) * 64 + l) * 4];
      #pragma unroll
      for (int r = 0; r < 4; ++r) {
        const int m = m0 + (i + 2) * 16 + (l >> 4) * 4 + r;
        #pragma unroll
        for (int j = 0; j < 4; ++j) {
          const int n = n0 + j * 16 + (l & 15);
          E[(size_t)m * DO + n] = acc[i + 2][j][r] + b2[n];
        }
      }
    }
  }
}

// ---------- scores: d-split partials (reads E directly) + reduce ----------
__global__ __launch_bounds__(256)
void score_partial(const float* __restrict__ E, const float* __restrict__ labels,
                   float* __restrict__ SP) {
  __shared__ float es[64][33];   // [d][b]
  __shared__ float ls[64][132];  // [d][l]
  const int tid = threadIdx.x;
  const int b0 = blockIdx.x * 32;
  const int d0 = blockIdx.y * 64;

  #pragma unroll
  for (int i = 0; i < 2; ++i) {
    const int fi = tid + i * 256;
    const int b = fi >> 4, dq = fi & 15;
    const float4 v = *(const float4*)&E[(size_t)(b0 + b) * DO + d0 + dq * 4];
    es[dq * 4 + 0][b] = v.x; es[dq * 4 + 1][b] = v.y;
    es[dq * 4 + 2][b] = v.z; es[dq * 4 + 3][b] = v.w;
  }
  #pragma unroll
  for (int i = 0; i < 8; ++i) {
    const int fi = tid + i * 256;
    const int lr = fi >> 4, dq = fi & 15;
    const float4 v = *(const float4*)&labels[(size_t)lr * DO + d0 + dq * 4];
    ls[dq * 4 + 0][lr] = v.x; ls[dq * 4 + 1][lr] = v.y;
    ls[dq * 4 + 2][lr] = v.z; ls[dq * 4 + 3][lr] = v.w;
  }
  __syncthreads();

  const int tb = tid & 15;   // b-pair
  const int tl = tid >> 4;   // label-octet
  float acc[2][8] = {};

  for (int dd = 0; dd < 64; ++dd) {
    const float e0 = es[dd][tb * 2 + 0];
    const float e1 = es[dd][tb * 2 + 1];
    const float4 l0 = *(const float4*)&ls[dd][tl * 8];
    const float4 l1 = *(const float4*)&ls[dd][tl * 8 + 4];
    const float lv[8] = {l0.x, l0.y, l0.z, l0.w, l1.x, l1.y, l1.z, l1.w};
    #pragma unroll
    for (int j = 0; j < 8; ++j) {
      float t0 = fmaxf(lv[j] - e0, 0.f); acc[0][j] = fmaf(t0, t0, acc[0][j]);
      float t1 = fmaxf(lv[j] - e1, 0.f); acc[1][j] = fmaf(t1, t1, acc[1][j]);
    }
  }

  float* SPz = SP + (size_t)blockIdx.y * (Bn * NL);
  #pragma unroll
  for (int i = 0; i < 2; ++i) {
    const size_t base = (size_t)(b0 + tb * 2 + i) * NL + tl * 8;
    float4 v0 = {acc[i][0], acc[i][1], acc[i][2], acc[i][3]};
    float4 v1 = {acc[i][4], acc[i][5], acc[i][6], acc[i][7]};
    *(float4*)&SPz[base]     = v0;
    *(float4*)&SPz[base + 4] = v1;
  }
}

__global__ __launch_bounds__(256)
void score_reduce(const float* __restrict__ SP, float* __restrict__ out) {
  const size_t i4 = (size_t)blockIdx.x * 256 + threadIdx.x;
  f32x4 s = ((const f32x4*)SP)[i4];
  #pragma unroll
  for (int c = 1; c < 16; ++c) s += ((const f32x4*)SP)[(size_t)c * 32768 + i4];
  f32x4 o = {-sqrtf(s[0]), -sqrtf(s[1]), -sqrtf(s[2]), -sqrtf(s[3])};
  ((f32x4*)out)[i4] = o;
}

extern "C" void kernel_launch(void* const* d_in, const int* in_sizes, int n_in,
                              void* d_out, int out_size, void* d_ws, size_t ws_size,
                              hipStream_t stream) {
  const float* sbj  = (const float*)d_in[0];
  const float* obj  = (const float*)d_in[1];
  const float* W1   = (const float*)d_in[2];
  const float* b1   = (const float*)d_in[3];
  const float* W2   = (const float*)d_in[4];
  const float* b2   = (const float*)d_in[5];
  const float* labs = (const float*)d_in[6];
  float* scores = (float*)d_out;
  char* ws = (char*)d_ws;

  // Layout (MB): Abf [0,8)  W1t [8,16)  W2t [16,18)  H [18,20)  E [20,24)
  //              P [24,56) = 8 x 4 MB    SP [56,64)
  unsigned short* Abf = (unsigned short*)(ws);
  unsigned short* W1t = (unsigned short*)(ws + (8ull << 20));
  unsigned short* W2t = (unsigned short*)(ws + (16ull << 20));
  unsigned short* H   = (unsigned short*)(ws + (18ull << 20));
  float* E  = (float*)(ws + (20ull << 20));
  float* P  = (float*)(ws + (24ull << 20));
  float* SP = (float*)(ws + (56ull << 20));

  dim3 blk(256);
  prep<<<dim3(2048 + 1280), blk, 0, stream>>>(sbj, obj, W1, W2, Abf, W1t, W2t);

  // GEMM1: K=4096, 128^2 tiles, split-K=8 (KSLICE=512), z = XCD
  mfma_gemm<512><<<dim3(512), blk, 0, stream>>>(Abf, W1t, P, K1);
  combine1<<<dim3(Bn), blk, 0, stream>>>(P, b1, H);
  // GEMM2: full-K, direct E output (no partials)
  gemm2_full<<<dim3(256), blk, 0, stream>>>(H, W2t, b2, E);
  // scores
  score_partial<<<dim3(32, 16), blk, 0, stream>>>(E, labs, SP);
  score_reduce<<<dim3(128), blk, 0, stream>>>(SP, scores);
}

// Round 12
// 132.871 us; speedup vs baseline: 5.4328x; 1.0270x over previous
//
#include <hip/hip_runtime.h>
#include <math.h>

constexpr int Bn = 1024, DH = 2048, K1 = 4096, DO = 1024, NL = 128;
constexpr int MN = Bn * DO;  // 1M elements

typedef __bf16 bf16x8 __attribute__((ext_vector_type(8)));
typedef short  s16x8  __attribute__((ext_vector_type(8)));
typedef float  f32x4  __attribute__((ext_vector_type(4)));

__device__ __forceinline__ unsigned short f2bf(float f) {
  union { float f; unsigned u; } v; v.f = f;
  unsigned r = v.u + 0x7FFFu + ((v.u >> 16) & 1u);  // RNE
  return (unsigned short)(r >> 16);
}
__device__ __forceinline__ float bf2f(unsigned h) {
  union { unsigned u; float f; } v; v.u = h << 16; return v.f;
}

// ---------- prep: concat+relu+bf16 (blocks 0..2047) + W1/W2 transposes ----------
__global__ __launch_bounds__(256)
void prep(const float* __restrict__ sbj, const float* __restrict__ obj,
          const float* __restrict__ W1, const float* __restrict__ W2,
          unsigned short* __restrict__ Abf,
          unsigned short* __restrict__ W1t, unsigned short* __restrict__ W2t) {
  const int tid = threadIdx.x;
  if (blockIdx.x < 2048) {
    const int t = blockIdx.x * 256 + tid;
    const int m = t >> 9;
    const int k = (t & 511) << 3;
    const float* src = (k < DH) ? sbj + (size_t)m * DH + k
                                : obj + (size_t)m * DH + (k - DH);
    const float4 a = ((const float4*)src)[0];
    const float4 b = ((const float4*)src)[1];
    uint4 o;
    o.x = (unsigned)f2bf(fmaxf(a.x, 0.f)) | ((unsigned)f2bf(fmaxf(a.y, 0.f)) << 16);
    o.y = (unsigned)f2bf(fmaxf(a.z, 0.f)) | ((unsigned)f2bf(fmaxf(a.w, 0.f)) << 16);
    o.z = (unsigned)f2bf(fmaxf(b.x, 0.f)) | ((unsigned)f2bf(fmaxf(b.y, 0.f)) << 16);
    o.w = (unsigned)f2bf(fmaxf(b.z, 0.f)) | ((unsigned)f2bf(fmaxf(b.w, 0.f)) << 16);
    *(uint4*)&Abf[(size_t)m * K1 + k] = o;
    return;
  }
  __shared__ float tl[64][65];
  const int tb = blockIdx.x - 2048;
  int by = tb >> 4;
  const int c0 = (tb & 15) * 64;
  const float* in; unsigned short* out; int R;
  if (by < 64) { in = W1; out = W1t; R = K1; }
  else         { in = W2; out = W2t; R = DO; by -= 64; }
  const int r0 = by * 64;
  {
    const int rr = tid >> 4, cc = (tid & 15) * 4;
    #pragma unroll
    for (int i = 0; i < 4; ++i) {
      const float4 v = *(const float4*)&in[(size_t)(r0 + rr + i * 16) * DO + c0 + cc];
      tl[rr + i * 16][cc + 0] = v.x; tl[rr + i * 16][cc + 1] = v.y;
      tl[rr + i * 16][cc + 2] = v.z; tl[rr + i * 16][cc + 3] = v.w;
    }
  }
  __syncthreads();
  {
    const int r4 = (tid & 15) * 4;
    #pragma unroll
    for (int i = 0; i < 4; ++i) {
      const int cr = i * 16 + (tid >> 4);
      uint2 o;
      o.x = (unsigned)f2bf(tl[r4 + 0][cr]) | ((unsigned)f2bf(tl[r4 + 1][cr]) << 16);
      o.y = (unsigned)f2bf(tl[r4 + 2][cr]) | ((unsigned)f2bf(tl[r4 + 3][cr]) << 16);
      *(uint2*)&out[(size_t)(c0 + cr) * R + r0 + r4] = o;
    }
  }
}

// ---------- GEMM1: 128x128 tile, 4 waves in 2x2 (64x64 quadrant each),
// BK=64, split-K=8 with z = XCD (bid&7): per-XCD slice (2 MB) L2-resident.
// Writes *bf16* partials P[z][1024][1024] (error ~2e-3, halves P traffic). ----------
template <int KSLICE>
__global__ __launch_bounds__(256, 2)
void mfma_gemm(const unsigned short* __restrict__ A,
               const unsigned short* __restrict__ Bt,
               unsigned short* __restrict__ P, int K) {
  __shared__ __align__(16) unsigned short smem[2 * 128 * 64];  // 32 KB
  unsigned short* LA = smem;
  unsigned short* LB = smem + 128 * 64;

  const int tid = threadIdx.x;
  const int w = tid >> 6, l = tid & 63;
  const int bid = blockIdx.x;
  const int z = bid & 7, t = bid >> 3;
  const int m0 = (t >> 3) * 128, n0 = (t & 7) * 128;
  const int kb = z * KSLICE;

  f32x4 acc[4][4] = {};

  constexpr int NIT = KSLICE / 64;
  for (int it = 0; it < NIT; ++it) {
    const int k0 = kb + it * 64;
    #pragma unroll
    for (int i = 0; i < 4; ++i) {
      const int c = i * 256 + tid, row = c >> 3, kc = c & 7;
      const int kcg = kc ^ (row & 7);
      __builtin_amdgcn_global_load_lds(
          (const __attribute__((address_space(1))) unsigned int*)(A + (size_t)(m0 + row) * K + k0 + kcg * 8),
          (__attribute__((address_space(3))) unsigned int*)&LA[c * 8], 16, 0, 0);
    }
    #pragma unroll
    for (int i = 0; i < 4; ++i) {
      const int c = i * 256 + tid, row = c >> 3, kc = c & 7;
      const int kcg = kc ^ (row & 7);
      __builtin_amdgcn_global_load_lds(
          (const __attribute__((address_space(1))) unsigned int*)(Bt + (size_t)(n0 + row) * K + k0 + kcg * 8),
          (__attribute__((address_space(3))) unsigned int*)&LB[c * 8], 16, 0, 0);
    }
    __syncthreads();

    #pragma unroll
    for (int s = 0; s < 2; ++s) {
      const int kcq = s * 4 + (l >> 4);
      bf16x8 af[4], bfr[4];
      #pragma unroll
      for (int i = 0; i < 4; ++i) {
        const int r = (w >> 1) * 64 + i * 16 + (l & 15);
        const int kca = kcq ^ (r & 7);
        af[i] = __builtin_bit_cast(bf16x8, *(const s16x8*)&LA[(r * 8 + kca) * 8]);
      }
      #pragma unroll
      for (int j = 0; j < 4; ++j) {
        const int rr = (w & 1) * 64 + j * 16 + (l & 15);
        const int kcb = kcq ^ (rr & 7);
        bfr[j] = __builtin_bit_cast(bf16x8, *(const s16x8*)&LB[(rr * 8 + kcb) * 8]);
      }
      #pragma unroll
      for (int i = 0; i < 4; ++i)
        #pragma unroll
        for (int j = 0; j < 4; ++j)
          acc[i][j] = __builtin_amdgcn_mfma_f32_16x16x32_bf16(af[i], bfr[j], acc[i][j], 0, 0, 0);
    }
    __syncthreads();
  }

  unsigned short* Pz = P + (size_t)z * MN;
  #pragma unroll
  for (int i = 0; i < 4; ++i) {
    #pragma unroll
    for (int r = 0; r < 4; ++r) {
      const int m = m0 + (w >> 1) * 64 + i * 16 + (l >> 4) * 4 + r;
      #pragma unroll
      for (int j = 0; j < 4; ++j) {
        const int n = n0 + (w & 1) * 64 + j * 16 + (l & 15);
        Pz[(size_t)m * DO + n] = f2bf(acc[i][j][r]);
      }
    }
  }
}

// ---------- combine1: H = relu(sum_z bf16 P[z] + b1) -> bf16 ----------
__global__ __launch_bounds__(256)
void combine1(const unsigned short* __restrict__ P, const float* __restrict__ bias,
              unsigned short* __restrict__ out) {
  const int row = blockIdx.x, t = threadIdx.x;
  const size_t base = (size_t)row * DO + t * 4;
  float s0 = 0.f, s1 = 0.f, s2 = 0.f, s3 = 0.f;
  #pragma unroll
  for (int c = 0; c < 8; ++c) {
    const uint2 wv = *(const uint2*)&P[(size_t)c * MN + base];
    s0 += bf2f(wv.x & 0xFFFFu); s1 += bf2f(wv.x >> 16);
    s2 += bf2f(wv.y & 0xFFFFu); s3 += bf2f(wv.y >> 16);
  }
  const f32x4 bb = *(const f32x4*)&bias[t * 4];
  s0 = fmaxf(s0 + bb[0], 0.f); s1 = fmaxf(s1 + bb[1], 0.f);
  s2 = fmaxf(s2 + bb[2], 0.f); s3 = fmaxf(s3 + bb[3], 0.f);
  uint2 o;
  o.x = (unsigned)f2bf(s0) | ((unsigned)f2bf(s1) << 16);
  o.y = (unsigned)f2bf(s2) | ((unsigned)f2bf(s3) << 16);
  *(uint2*)&out[base] = o;
}

// ---------- GEMM2 (full-K): 64x64 tile, in-block 4-wave k-split, BK=128,
// LDS tree-reduce, epilogue writes E = sum + b2 directly (fp32). ----------
__global__ __launch_bounds__(256, 4)
void gemm2_full(const unsigned short* __restrict__ A,
                const unsigned short* __restrict__ Bt,
                const float* __restrict__ b2, float* __restrict__ E) {
  __shared__ __align__(16) unsigned short smem[2 * 64 * 128];  // 32 KB
  unsigned short* LA = smem;
  unsigned short* LB = smem + 64 * 128;

  const int tid = threadIdx.x;
  const int w = tid >> 6, l = tid & 63;
  const int bid = blockIdx.x;
  const int m0 = (bid >> 4) * 64, n0 = (bid & 15) * 64;

  f32x4 acc[4][4] = {};

  for (int it = 0; it < 8; ++it) {  // K=1024, BK=128
    const int k0 = it * 128;
    #pragma unroll
    for (int i = 0; i < 4; ++i) {
      const int c = i * 256 + tid, m = c >> 4, kc = c & 15;
      const int kcg = (kc & 8) | ((kc & 7) ^ (m & 7));
      __builtin_amdgcn_global_load_lds(
          (const __attribute__((address_space(1))) unsigned int*)(A + (size_t)(m0 + m) * DO + k0 + kcg * 8),
          (__attribute__((address_space(3))) unsigned int*)&LA[c * 8], 16, 0, 0);
    }
    #pragma unroll
    for (int i = 0; i < 4; ++i) {
      const int c = i * 256 + tid, n = c >> 4, kc = c & 15;
      const int kcg = (kc & 8) | ((kc & 7) ^ (n & 7));
      __builtin_amdgcn_global_load_lds(
          (const __attribute__((address_space(1))) unsigned int*)(Bt + (size_t)(n0 + n) * DO + k0 + kcg * 8),
          (__attribute__((address_space(3))) unsigned int*)&LB[c * 8], 16, 0, 0);
    }
    __syncthreads();

    const int kcq = w * 4 + (l >> 4);
    bf16x8 af[4], bfr[4];
    #pragma unroll
    for (int i = 0; i < 4; ++i) {
      const int r = i * 16 + (l & 15);
      const int kca = (kcq & 8) | ((kcq & 7) ^ (r & 7));
      af[i]  = __builtin_bit_cast(bf16x8, *(const s16x8*)&LA[(r * 16 + kca) * 8]);
      bfr[i] = __builtin_bit_cast(bf16x8, *(const s16x8*)&LB[(r * 16 + kca) * 8]);
    }
    #pragma unroll
    for (int i = 0; i < 4; ++i)
      #pragma unroll
      for (int j = 0; j < 4; ++j)
        acc[i][j] = __builtin_amdgcn_mfma_f32_16x16x32_bf16(af[i], bfr[j], acc[i][j], 0, 0, 0);
    __syncthreads();
  }

  float* red = (float*)smem;
  if (w >= 2) {
    #pragma unroll
    for (int i = 0; i < 4; ++i)
      #pragma unroll
      for (int j = 0; j < 4; ++j)
        *(f32x4*)&red[(w - 2) * 4096 + ((i * 4 + j) * 64 + l) * 4] = acc[i][j];
  }
  __syncthreads();
  if (w < 2) {
    #pragma unroll
    for (int i = 0; i < 4; ++i)
      #pragma unroll
      for (int j = 0; j < 4; ++j)
        acc[i][j] += *(const f32x4*)&red[w * 4096 + ((i * 4 + j) * 64 + l) * 4];
  }
  __syncthreads();
  if (w == 1) {
    #pragma unroll
    for (int i = 0; i < 2; ++i)
      #pragma unroll
      for (int j = 0; j < 4; ++j)
        *(f32x4*)&red[((i * 4 + j) * 64 + l) * 4] = acc[i][j];
  } else if (w == 0) {
    #pragma unroll
    for (int i = 0; i < 2; ++i)
      #pragma unroll
      for (int j = 0; j < 4; ++j)
        *(f32x4*)&red[2048 + ((i * 4 + j) * 64 + l) * 4] = acc[i + 2][j];
  }
  __syncthreads();
  if (w >= 2) return;

  if (w == 0) {
    #pragma unroll
    for (int i = 0; i < 2; ++i) {
      #pragma unroll
      for (int j = 0; j < 4; ++j)
        acc[i][j] += *(const f32x4*)&red[((i * 4 + j) * 64 + l) * 4];
      #pragma unroll
      for (int r = 0; r < 4; ++r) {
        const int m = m0 + i * 16 + (l >> 4) * 4 + r;
        #pragma unroll
        for (int j = 0; j < 4; ++j) {
          const int n = n0 + j * 16 + (l & 15);
          E[(size_t)m * DO + n] = acc[i][j][r] + b2[n];
        }
      }
    }
  } else {
    #pragma unroll
    for (int i = 0; i < 2; ++i) {
      #pragma unroll
      for (int j = 0; j < 4; ++j)
        acc[i + 2][j] += *(const f32x4*)&red[2048 + ((i * 4 + j) * 64 + l) * 4];
      #pragma unroll
      for (int r = 0; r < 4; ++r) {
        const int m = m0 + (i + 2) * 16 + (l >> 4) * 4 + r;
        #pragma unroll
        for (int j = 0; j < 4; ++j) {
          const int n = n0 + j * 16 + (l & 15);
          E[(size_t)m * DO + n] = acc[i + 2][j][r] + b2[n];
        }
      }
    }
  }
}

// ---------- scores: d-split partials (reads E directly) + reduce ----------
__global__ __launch_bounds__(256)
void score_partial(const float* __restrict__ E, const float* __restrict__ labels,
                   float* __restrict__ SP) {
  __shared__ float es[64][33];   // [d][b]
  __shared__ float ls[64][132];  // [d][l]
  const int tid = threadIdx.x;
  const int b0 = blockIdx.x * 32;
  const int d0 = blockIdx.y * 64;

  #pragma unroll
  for (int i = 0; i < 2; ++i) {
    const int fi = tid + i * 256;
    const int b = fi >> 4, dq = fi & 15;
    const float4 v = *(const float4*)&E[(size_t)(b0 + b) * DO + d0 + dq * 4];
    es[dq * 4 + 0][b] = v.x; es[dq * 4 + 1][b] = v.y;
    es[dq * 4 + 2][b] = v.z; es[dq * 4 + 3][b] = v.w;
  }
  #pragma unroll
  for (int i = 0; i < 8; ++i) {
    const int fi = tid + i * 256;
    const int lr = fi >> 4, dq = fi & 15;
    const float4 v = *(const float4*)&labels[(size_t)lr * DO + d0 + dq * 4];
    ls[dq * 4 + 0][lr] = v.x; ls[dq * 4 + 1][lr] = v.y;
    ls[dq * 4 + 2][lr] = v.z; ls[dq * 4 + 3][lr] = v.w;
  }
  __syncthreads();

  const int tb = tid & 15;   // b-pair
  const int tl = tid >> 4;   // label-octet
  float acc[2][8] = {};

  for (int dd = 0; dd < 64; ++dd) {
    const float e0 = es[dd][tb * 2 + 0];
    const float e1 = es[dd][tb * 2 + 1];
    const float4 l0 = *(const float4*)&ls[dd][tl * 8];
    const float4 l1 = *(const float4*)&ls[dd][tl * 8 + 4];
    const float lv[8] = {l0.x, l0.y, l0.z, l0.w, l1.x, l1.y, l1.z, l1.w};
    #pragma unroll
    for (int j = 0; j < 8; ++j) {
      float t0 = fmaxf(lv[j] - e0, 0.f); acc[0][j] = fmaf(t0, t0, acc[0][j]);
      float t1 = fmaxf(lv[j] - e1, 0.f); acc[1][j] = fmaf(t1, t1, acc[1][j]);
    }
  }

  float* SPz = SP + (size_t)blockIdx.y * (Bn * NL);
  #pragma unroll
  for (int i = 0; i < 2; ++i) {
    const size_t base = (size_t)(b0 + tb * 2 + i) * NL + tl * 8;
    float4 v0 = {acc[i][0], acc[i][1], acc[i][2], acc[i][3]};
    float4 v1 = {acc[i][4], acc[i][5], acc[i][6], acc[i][7]};
    *(float4*)&SPz[base]     = v0;
    *(float4*)&SPz[base + 4] = v1;
  }
}

__global__ __launch_bounds__(256)
void score_reduce(const float* __restrict__ SP, float* __restrict__ out) {
  const size_t i4 = (size_t)blockIdx.x * 256 + threadIdx.x;
  f32x4 s = ((const f32x4*)SP)[i4];
  #pragma unroll
  for (int c = 1; c < 16; ++c) s += ((const f32x4*)SP)[(size_t)c * 32768 + i4];
  f32x4 o = {-sqrtf(s[0]), -sqrtf(s[1]), -sqrtf(s[2]), -sqrtf(s[3])};
  ((f32x4*)out)[i4] = o;
}

extern "C" void kernel_launch(void* const* d_in, const int* in_sizes, int n_in,
                              void* d_out, int out_size, void* d_ws, size_t ws_size,
                              hipStream_t stream) {
  const float* sbj  = (const float*)d_in[0];
  const float* obj  = (const float*)d_in[1];
  const float* W1   = (const float*)d_in[2];
  const float* b1   = (const float*)d_in[3];
  const float* W2   = (const float*)d_in[4];
  const float* b2   = (const float*)d_in[5];
  const float* labs = (const float*)d_in[6];
  float* scores = (float*)d_out;
  char* ws = (char*)d_ws;

  // Layout (MB): Abf [0,8)  W1t [8,16)  W2t [16,18)  H [18,20)  E [20,24)
  //              P [24,40) = 8 x 2 MB bf16    SP [40,48)
  unsigned short* Abf = (unsigned short*)(ws);
  unsigned short* W1t = (unsigned short*)(ws + (8ull << 20));
  unsigned short* W2t = (unsigned short*)(ws + (16ull << 20));
  unsigned short* H   = (unsigned short*)(ws + (18ull << 20));
  float* E  = (float*)(ws + (20ull << 20));
  unsigned short* P = (unsigned short*)(ws + (24ull << 20));
  float* SP = (float*)(ws + (40ull << 20));

  dim3 blk(256);
  prep<<<dim3(2048 + 1280), blk, 0, stream>>>(sbj, obj, W1, W2, Abf, W1t, W2t);

  // GEMM1: K=4096, 128^2 tiles, split-K=8 (KSLICE=512), z = XCD, bf16 partials
  mfma_gemm<512><<<dim3(512), blk, 0, stream>>>(Abf, W1t, P, K1);
  combine1<<<dim3(Bn), blk, 0, stream>>>(P, b1, H);
  // GEMM2: full-K, direct E output (no partials)
  gemm2_full<<<dim3(256), blk, 0, stream>>>(H, W2t, b2, E);
  // scores
  score_partial<<<dim3(32, 16), blk, 0, stream>>>(E, labs, SP);
  score_reduce<<<dim3(128), blk, 0, stream>>>(SP, scores);
}